// Round 10
// baseline (180.505 us; speedup 1.0000x reference)
//
#include <hip/hip_runtime.h>
#include <hip/hip_bf16.h>

// B=4, L=2048, DIM=512, H=8, D=64, fp32 in/out.
// pack fp32->fp16 (log2e folded into wq) -> fused QKV MFMA GEMM (V^T via
// in-LDS transpose epilogue) -> 32x32x16-MFMA flash attn (split-K wave
// pairs, gl2lds swizzled staging, permlane32_swap P-transform) -> out GEMM.

#define Bsz 4
#define Lsz 2048
#define DIMsz 512
#define Hsz 8
#define Dsz 64

typedef _Float16 f16;
typedef __attribute__((ext_vector_type(8))) _Float16 f16x8;
typedef __attribute__((ext_vector_type(4))) _Float16 f16x4;
typedef __attribute__((ext_vector_type(2))) __fp16 fp16x2;  // builtin ret type
typedef __attribute__((ext_vector_type(4))) float f32x4;
typedef __attribute__((ext_vector_type(16))) float f32x16;
typedef unsigned int u32;
typedef __attribute__((ext_vector_type(2))) unsigned int u32x2;

#if __has_builtin(__builtin_amdgcn_exp2f)
#define EXP2(x) __builtin_amdgcn_exp2f(x)
#else
#define EXP2(x) __expf(0.6931471805599453f * (x))
#endif

__device__ __forceinline__ u32 pack2(float a, float b) {
#if __has_builtin(__builtin_amdgcn_cvt_pkrtz)
    fp16x2 h = __builtin_amdgcn_cvt_pkrtz(a, b);
    return __builtin_bit_cast(u32, h);
#else
    fp16x2 h; h.x = (__fp16)a; h.y = (__fp16)b;
    return __builtin_bit_cast(u32, h);
#endif
}

// Cross-half exchange for the 32x32 C->B P-transform:
// a' = (h=0: own a | h=1: partner's b);  b' = (h=0: partner's a | h=1: own b)
#if __has_builtin(__builtin_amdgcn_permlane32_swap)
__device__ __forceinline__ void plswap(u32& a, u32& b) {
    u32x2 r = __builtin_amdgcn_permlane32_swap(a, b, false, false);
    a = r.x; b = r.y;
}
#else
__device__ __forceinline__ void plswap(u32& a, u32& b) {
    u32 sa = (u32)__shfl_xor((int)a, 32);
    u32 sb = (u32)__shfl_xor((int)b, 32);
    bool hi = (threadIdx.x & 32) != 0;
    u32 na = hi ? sb : a;
    u32 nb = hi ? b : sa;
    a = na; b = nb;
}
#endif

__device__ __forceinline__ void gl2lds16(const void* g, void* l) {
    __builtin_amdgcn_global_load_lds(
        (const __attribute__((address_space(1))) u32*)g,
        (__attribute__((address_space(3))) u32*)l, 16, 0, 0);
}

// ---------------- pack: fp32 -> fp16 ----------------------------------------
// wq scale = 0.125 * log2(e): scores come out of QK^T in log2 domain.
// 1D grid: [0,4096) = x; then 4x256 blocks for wq/wk/wv/wo.
__global__ __launch_bounds__(256) void pack_f16(
    const float* __restrict__ x, const float* __restrict__ wq,
    const float* __restrict__ wk, const float* __restrict__ wv,
    const float* __restrict__ wo,
    f16* __restrict__ xh, f16* __restrict__ w3h, f16* __restrict__ woh)
{
    int bx = blockIdx.x, seg, blk;
    if (bx < 4096) { seg = 0; blk = bx; }
    else { seg = 1 + ((bx - 4096) >> 8); blk = (bx - 4096) & 255; }
    const float* s; f16* d; float sc = 1.0f;
    switch (seg) {
        case 0: s = x;  d = xh;            break;
        case 1: s = wq; d = w3h;           sc = 0.18033688011112042f; break;
        case 2: s = wk; d = w3h + 262144;  break;
        case 3: s = wv; d = w3h + 524288;  break;
        default: s = wo; d = woh;          break;
    }
    int i = (blk * 256 + threadIdx.x) * 4;
    float4 v = *(const float4*)(s + i);
    f16x4 o;
    o.x = (f16)(v.x * sc); o.y = (f16)(v.y * sc);
    o.z = (f16)(v.z * sc); o.w = (f16)(v.w * sc);
    *(f16x4*)(d + i) = o;
}

// ---------------- fused QKV MFMA GEMM ----------------------------------------
// C[8192][1536] = xh @ w3h^T. 128x128 tile, BK=32, global_load_lds w16,
// XOR-swizzled LDS. grid (12, 64), block 256 (4 waves 2x2).
__global__ __launch_bounds__(256) void gemm_qkv_f16(
    const f16* __restrict__ A, const f16* __restrict__ B,
    f16* __restrict__ qh, f16* __restrict__ kh, f16* __restrict__ vth)
{
    __shared__ __align__(16) char smem[17408];   // staging 16K | Tv 17408
    f16* Ash = (f16*)smem;
    f16* Bsh = (f16*)(smem + 8192);

    const int tid = threadIdx.x;
    const int w = tid >> 6, lane = tid & 63;
    const int quad = lane >> 4, low = lane & 15;
    const int wm = w >> 1, wn = w & 1;
    const int m0 = blockIdx.y * 128, n0 = blockIdx.x * 128;

    f32x4 acc[4][4];
    #pragma unroll
    for (int i = 0; i < 4; i++)
        #pragma unroll
        for (int j = 0; j < 4; j++) acc[i][j] = (f32x4){0.f, 0.f, 0.f, 0.f};

    #pragma unroll 1
    for (int k0 = 0; k0 < DIMsz; k0 += 32) {
        __syncthreads();
        #pragma unroll
        for (int j = 0; j < 2; j++) {
            int t = j * 256 + tid;
            int r = t >> 2, g = t & 3;
            int gc = (g ^ ((r >> 1) & 3)) * 8;
            char* lb = (char*)Ash + (j * 256 + w * 64) * 16;
            gl2lds16(A + (size_t)(m0 + r) * DIMsz + k0 + gc, lb);
            char* lb2 = (char*)Bsh + (j * 256 + w * 64) * 16;
            gl2lds16(B + (size_t)(n0 + r) * DIMsz + k0 + gc, lb2);
        }
        __syncthreads();

        f16x8 af[4], bf[4];
        #pragma unroll
        for (int mt = 0; mt < 4; mt++) {
            int ar = wm * 64 + mt * 16 + low;
            af[mt] = *(const f16x8*)&Ash[ar * 32 + ((quad ^ ((ar >> 1) & 3)) << 3)];
        }
        #pragma unroll
        for (int nt = 0; nt < 4; nt++) {
            int br = wn * 64 + nt * 16 + low;
            bf[nt] = *(const f16x8*)&Bsh[br * 32 + ((quad ^ ((br >> 1) & 3)) << 3)];
        }
        #pragma unroll
        for (int mt = 0; mt < 4; mt++)
            #pragma unroll
            for (int nt = 0; nt < 4; nt++)
                acc[mt][nt] = __builtin_amdgcn_mfma_f32_16x16x32_f16(
                    af[mt], bf[nt], acc[mt][nt], 0, 0, 0);
    }

    const int proj = n0 >> 9;                 // uniform per block
    if (proj < 2) {
        f16* dst = (proj == 0) ? qh : kh;
        #pragma unroll
        for (int nt = 0; nt < 4; nt++) {
            int n = n0 + wn * 64 + nt * 16 + low;
            int c = n & 511, h = c >> 6, d = c & 63;
            #pragma unroll
            for (int mt = 0; mt < 4; mt++)
                #pragma unroll
                for (int r = 0; r < 4; r++) {
                    int m = m0 + wm * 64 + mt * 16 + quad * 4 + r;
                    int b_ = m >> 11, l = m & (Lsz - 1);
                    size_t bh = (size_t)(b_ * Hsz + h);
                    dst[(bh * Lsz + l) * Dsz + d] = (f16)acc[mt][nt][r];
                }
        }
    } else {
        // v: transpose per head through LDS, then coalesced stores
        const int hb = (n0 & 511) >> 6;
        f16* Tv = (f16*)smem;                 // [64 d][136]
        const int b_ = m0 >> 11, l0 = m0 & (Lsz - 1);
        #pragma unroll 1
        for (int hs = 0; hs < 2; hs++) {
            __syncthreads();
            if (wn == hs) {
                #pragma unroll
                for (int nt = 0; nt < 4; nt++) {
                    int d = nt * 16 + low;
                    #pragma unroll
                    for (int mt = 0; mt < 4; mt++)
                        #pragma unroll
                        for (int r = 0; r < 4; r++) {
                            int l = wm * 64 + mt * 16 + quad * 4 + r;
                            Tv[d * 136 + l] = (f16)acc[mt][nt][r];
                        }
                }
            }
            __syncthreads();
            int d = tid >> 2, seg = tid & 3;
            size_t bh = (size_t)(b_ * Hsz + hb + hs);
            f16* dstp = vth + (bh * 64 + d) * (size_t)Lsz + l0 + seg * 32;
            const f16* srcp = Tv + d * 136 + seg * 32;
            #pragma unroll
            for (int j = 0; j < 4; j++)
                *(f16x8*)(dstp + j * 8) = *(const f16x8*)(srcp + j * 8);
        }
    }
}

// ---------------- MFMA flash attention (32x32x16, split-K wave pairs) --------
// grid (B*H=32 fastest -> XCD locality, L/64=32), block 256 = 4 waves.
// Waves {0,1} share q-tile 0 (32 q), waves {2,3} q-tile 1; wave kw owns
// chunk keys kw*32..+31 (split-K; O/lsum merged at the end). K/V staged via
// global_load_lds into col-XOR-swizzled LDS. P goes C-layout -> B-operand
// IN REGISTERS via v_permlane32_swap (no LDS round-trip).
__global__ __launch_bounds__(256) void attn_mfma(
    const f16* __restrict__ q, const f16* __restrict__ k,
    const f16* __restrict__ vt, f16* __restrict__ ctx)
{
    __shared__ __align__(16) char smem[16384];   // Ks 8K | Vs 8K ; reused: O-merge
    __shared__ float Ls[2][32];                  // cross-wave lsum merge

    f16* Ks = (f16*)smem;            // [64 key][64 d], cols swizzled by row&7
    f16* Vs = (f16*)(smem + 8192);   // [64 d][64 key], cols swizzled by row&7

    const int tid = threadIdx.x;
    const int w = tid >> 6, lane = tid & 63;
    const int col = lane & 31;       // q column / A-operand m index
    const int h = lane >> 5;         // half-wave: k-offset h*8
    const int bh = blockIdx.x;       // fastest -> 4 heads per XCD
    const int qb = blockIdx.y;
    const int grp = w >> 1;          // q-tile within block
    const int kw = w & 1;            // owned key half
    const int q0w = qb * 64 + grp * 32;
    const size_t kvb = (size_t)bh * Lsz;

    // Q B-frags: B[k=d][n=q]: lane n=col, k = s*16 + h*8 + j
    f16x8 qf[4];
    #pragma unroll
    for (int s = 0; s < 4; s++)
        qf[s] = *(const f16x8*)(q + (kvb + q0w + col) * Dsz + s * 16 + h * 8);

    f32x16 acc[2];                   // O^T partials: [dt][reg], cols=q
    #pragma unroll
    for (int dt = 0; dt < 2; dt++)
        #pragma unroll
        for (int i = 0; i < 16; i++) acc[dt][i] = 0.f;
    float lsum = 0.f;

    #pragma unroll 1
    for (int s0 = 0; s0 < Lsz; s0 += 64) {
        __syncthreads();
        #pragma unroll
        for (int i = 0; i < 2; i++) {
            int idx = i * 256 + tid;
            int r = idx >> 3, g = idx & 7;
            int gc = (g ^ (r & 7)) * 8;
            char* kl = (char*)Ks + (i * 256 + w * 64) * 16;   // wave-uniform base
            char* vl = (char*)Vs + (i * 256 + w * 64) * 16;
            gl2lds16(k + (kvb + s0 + r) * Dsz + gc, kl);
            gl2lds16(vt + ((size_t)bh * Dsz + r) * Lsz + s0 + gc, vl);
        }
        __syncthreads();

        // ---- S^T (own 32 keys x 32 q): A = K rows, 4 k-steps over d ----
        f32x16 st;
        #pragma unroll
        for (int i = 0; i < 16; i++) st[i] = 0.f;
        #pragma unroll
        for (int s = 0; s < 4; s++) {
            f16x8 kf = *(const f16x8*)(Ks + (kw * 32 + col) * 64 +
                           (((s * 2 + h) ^ (col & 7)) << 3));
            st = __builtin_amdgcn_mfma_f32_32x32x16_f16(kf, qf[s], st, 0, 0, 0);
        }

        // ---- p = exp2(s); diag zero (wave-uniform chunk+half test) ----
        float pv[16];
        #pragma unroll
        for (int i = 0; i < 16; i++) pv[i] = EXP2(st[i]);
        if (s0 == qb * 64 && kw == grp) {
            #pragma unroll
            for (int i = 0; i < 16; i++) {
                int row = (i & 3) + 8 * (i >> 2) + 4 * h;
                pv[i] = (row == col) ? 0.f : pv[i];
            }
        }
        #pragma unroll
        for (int i = 0; i < 16; i++) lsum += pv[i];

        // ---- pack adjacent-key pairs (C rows r2=0..3 are consecutive),
        //      then C->B transform fully in registers via permlane32_swap:
        //      pair_idx(j,h) = 4*(j>>1) + 2h + (j&1); frag needs ks*8+4h+jj ----
        u32 P2[8];
        #pragma unroll
        for (int j = 0; j < 8; j++)
            P2[j] = pack2(pv[2 * j], pv[2 * j + 1]);
        plswap(P2[0], P2[2]); plswap(P2[1], P2[3]);
        plswap(P2[4], P2[6]); plswap(P2[5], P2[7]);
        union { u32 u[4]; f16x8 v; } pf[2];
        #pragma unroll
        for (int jj = 0; jj < 4; jj++) { pf[0].u[jj] = P2[jj]; pf[1].u[jj] = P2[4 + jj]; }

        // ---- O^T += V^T . P over own 32 keys: A = V^T[d][key] ----
        #pragma unroll
        for (int dt = 0; dt < 2; dt++)
            #pragma unroll
            for (int ks = 0; ks < 2; ks++) {
                f16x8 vf = *(const f16x8*)(Vs + (dt * 32 + col) * 64 +
                               (((kw * 4 + ks * 2 + h) ^ (col & 7)) << 3));
                acc[dt] = __builtin_amdgcn_mfma_f32_32x32x16_f16(
                    vf, pf[ks].v, acc[dt], 0, 0, 0);
            }
    }

    lsum += __shfl_xor(lsum, 32);    // reduce over half-wave split of keys

    // ---- cross-wave split-K merge through reused staging LDS (fp32) ----
    __syncthreads();
    float* Om = (float*)smem;        // [grp][64 d][32 q] = 16 KB
    if (kw == 1) {
        float* og = Om + grp * 64 * 32;
        #pragma unroll
        for (int dt = 0; dt < 2; dt++)
            #pragma unroll
            for (int i = 0; i < 16; i++) {
                int row = (i & 3) + 8 * (i >> 2) + 4 * h;
                og[(dt * 32 + row) * 32 + col] = acc[dt][i];
            }
        if (h == 0) Ls[grp][col] = lsum;
    }
    __syncthreads();
    if (kw == 0) {
        const float* og = Om + grp * 64 * 32;
        #pragma unroll
        for (int dt = 0; dt < 2; dt++)
            #pragma unroll
            for (int i = 0; i < 16; i++) {
                int row = (i & 3) + 8 * (i >> 2) + 4 * h;
                acc[dt][i] += og[(dt * 32 + row) * 32 + col];
            }
        lsum += Ls[grp][col];
        const float inv = 1.0f / lsum;

        // store: lane q = q0w+col; regs 4*r4..+3 are consecutive d -> f16x4
        const int b = bh >> 3, hh = bh & 7;
        f16* op = ctx + ((size_t)(b * Lsz + q0w + col)) * DIMsz + hh * 64;
        #pragma unroll
        for (int dt = 0; dt < 2; dt++)
            #pragma unroll
            for (int r4 = 0; r4 < 4; r4++) {
                f16x4 o;
                o.x = (f16)(acc[dt][4 * r4 + 0] * inv);
                o.y = (f16)(acc[dt][4 * r4 + 1] * inv);
                o.z = (f16)(acc[dt][4 * r4 + 2] * inv);
                o.w = (f16)(acc[dt][4 * r4 + 3] * inv);
                *(f16x4*)(op + dt * 32 + 8 * r4 + 4 * h) = o;
            }
    }
}

// ---------------- out-proj MFMA GEMM: out(fp32) = ctx @ wo^T -----------------
// 64x64 tiles, BK=32, grid (8, 128) = 1024 blocks (4/CU).
__global__ __launch_bounds__(256) void gemm_out_f16(
    const f16* __restrict__ A, const f16* __restrict__ B,
    float* __restrict__ C)
{
    __shared__ f16 Ash[64 * 32];
    __shared__ f16 Bsh[64 * 32];
    const int tid = threadIdx.x;
    const int w = tid >> 6, lane = tid & 63;
    const int quad = lane >> 4, low = lane & 15;
    const int wm = w >> 1, wn = w & 1;
    const int m0 = blockIdx.y * 64, n0 = blockIdx.x * 64;

    f32x4 acc[2][2];
    #pragma unroll
    for (int i = 0; i < 2; i++)
        #pragma unroll
        for (int j = 0; j < 2; j++) acc[i][j] = (f32x4){0.f, 0.f, 0.f, 0.f};

    #pragma unroll 1
    for (int k0 = 0; k0 < DIMsz; k0 += 32) {
        __syncthreads();
        {
            int r = tid >> 2, g = tid & 3;
            int gc = (g ^ ((r >> 1) & 3)) * 8;
            gl2lds16(A + (size_t)(m0 + r) * DIMsz + k0 + gc, (char*)Ash + w * 64 * 16);
            gl2lds16(B + (size_t)(n0 + r) * DIMsz + k0 + gc, (char*)Bsh + w * 64 * 16);
        }
        __syncthreads();

        f16x8 af[2], bf[2];
        #pragma unroll
        for (int mt = 0; mt < 2; mt++) {
            int ar = wm * 32 + mt * 16 + low;
            af[mt] = *(const f16x8*)&Ash[ar * 32 + ((quad ^ ((ar >> 1) & 3)) << 3)];
        }
        #pragma unroll
        for (int nt = 0; nt < 2; nt++) {
            int br = wn * 32 + nt * 16 + low;
            bf[nt] = *(const f16x8*)&Bsh[br * 32 + ((quad ^ ((br >> 1) & 3)) << 3)];
        }
        #pragma unroll
        for (int mt = 0; mt < 2; mt++)
            #pragma unroll
            for (int nt = 0; nt < 2; nt++)
                acc[mt][nt] = __builtin_amdgcn_mfma_f32_16x16x32_f16(
                    af[mt], bf[nt], acc[mt][nt], 0, 0, 0);
    }

    #pragma unroll
    for (int mt = 0; mt < 2; mt++)
        #pragma unroll
        for (int r = 0; r < 4; r++) {
            int m = m0 + wm * 32 + mt * 16 + quad * 4 + r;
            #pragma unroll
            for (int nt = 0; nt < 2; nt++) {
                int n = n0 + wn * 32 + nt * 16 + low;
                C[(size_t)m * DIMsz + n] = acc[mt][nt][r];
            }
        }
}

extern "C" void kernel_launch(void* const* d_in, const int* in_sizes, int n_in,
                              void* d_out, int out_size, void* d_ws, size_t ws_size,
                              hipStream_t stream) {
    const float* x  = (const float*)d_in[0];
    const float* wq = (const float*)d_in[1];
    const float* wk = (const float*)d_in[2];
    const float* wv = (const float*)d_in[3];
    const float* wo = (const float*)d_in[4];
    float* out = (float*)d_out;

    const size_t NTOK = (size_t)Bsz * Lsz;   // 8192
    const size_t XSZ  = NTOK * DIMsz;        // 4,194,304

    f16* xh   = (f16*)d_ws;                  // 8 MB
    f16* w3h  = xh + XSZ;                    // 1.5 MB  [1536][512]
    f16* woh  = w3h + 3 * 262144;            // 0.5 MB
    f16* qh   = woh + 262144;                // 8 MB [bh][l][d] (scale*log2e)
    f16* kh   = qh + XSZ;                    // 8 MB [bh][l][d]
    f16* vth  = kh + XSZ;                    // 8 MB [bh][d][l]
    f16* ctxh = vth + XSZ;                   // 8 MB [b*l][512]

    pack_f16<<<5120, 256, 0, stream>>>(x, wq, wk, wv, wo, xh, w3h, woh);

    dim3 g1(1536 / 128, NTOK / 128);         // (12, 64)
    gemm_qkv_f16<<<g1, 256, 0, stream>>>(xh, w3h, qh, kh, vth);

    dim3 g2(Bsz * Hsz, Lsz / 64);            // (32 bh, 32 qb) — bh fastest
    attn_mfma<<<g2, 256, 0, stream>>>(qh, kh, vth, ctxh);

    dim3 g3(DIMsz / 64, NTOK / 64);          // (8, 128)
    gemm_out_f16<<<g3, 256, 0, stream>>>(ctxh, woh, out);
}

// Round 11
// 168.460 us; speedup vs baseline: 1.0715x; 1.0715x over previous
//
#include <hip/hip_runtime.h>
#include <hip/hip_bf16.h>

// B=4, L=2048, DIM=512, H=8, D=64, fp32 in/out.
// pack fp32->fp16 (log2e folded into wq) -> fused QKV MFMA GEMM (BK=64, V^T
// via in-LDS transpose epilogue) -> 32x32x16-MFMA flash attn (split-K wave
// pairs, 128-key staging rounds, permlane32_swap P-transform) -> out GEMM.

#define Bsz 4
#define Lsz 2048
#define DIMsz 512
#define Hsz 8
#define Dsz 64

typedef _Float16 f16;
typedef __attribute__((ext_vector_type(8))) _Float16 f16x8;
typedef __attribute__((ext_vector_type(4))) _Float16 f16x4;
typedef __attribute__((ext_vector_type(2))) __fp16 fp16x2;  // builtin ret type
typedef __attribute__((ext_vector_type(4))) float f32x4;
typedef __attribute__((ext_vector_type(16))) float f32x16;
typedef unsigned int u32;
typedef __attribute__((ext_vector_type(2))) unsigned int u32x2;

#if __has_builtin(__builtin_amdgcn_exp2f)
#define EXP2(x) __builtin_amdgcn_exp2f(x)
#else
#define EXP2(x) __expf(0.6931471805599453f * (x))
#endif

__device__ __forceinline__ u32 pack2(float a, float b) {
#if __has_builtin(__builtin_amdgcn_cvt_pkrtz)
    fp16x2 h = __builtin_amdgcn_cvt_pkrtz(a, b);
    return __builtin_bit_cast(u32, h);
#else
    fp16x2 h; h.x = (__fp16)a; h.y = (__fp16)b;
    return __builtin_bit_cast(u32, h);
#endif
}

// Cross-half exchange for the 32x32 C->B P-transform.
#if __has_builtin(__builtin_amdgcn_permlane32_swap)
__device__ __forceinline__ void plswap(u32& a, u32& b) {
    u32x2 r = __builtin_amdgcn_permlane32_swap(a, b, false, false);
    a = r.x; b = r.y;
}
#else
__device__ __forceinline__ void plswap(u32& a, u32& b) {
    u32 sa = (u32)__shfl_xor((int)a, 32);
    u32 sb = (u32)__shfl_xor((int)b, 32);
    bool hi = (threadIdx.x & 32) != 0;
    u32 na = hi ? sb : a;
    u32 nb = hi ? b : sa;
    a = na; b = nb;
}
#endif

__device__ __forceinline__ void gl2lds16(const void* g, void* l) {
    __builtin_amdgcn_global_load_lds(
        (const __attribute__((address_space(1))) u32*)g,
        (__attribute__((address_space(3))) u32*)l, 16, 0, 0);
}

// ---------------- pack: fp32 -> fp16 ----------------------------------------
// wq scale = 0.125 * log2(e): scores come out of QK^T in log2 domain.
__global__ __launch_bounds__(256) void pack_f16(
    const float* __restrict__ x, const float* __restrict__ wq,
    const float* __restrict__ wk, const float* __restrict__ wv,
    const float* __restrict__ wo,
    f16* __restrict__ xh, f16* __restrict__ w3h, f16* __restrict__ woh)
{
    int bx = blockIdx.x, seg, blk;
    if (bx < 4096) { seg = 0; blk = bx; }
    else { seg = 1 + ((bx - 4096) >> 8); blk = (bx - 4096) & 255; }
    const float* s; f16* d; float sc = 1.0f;
    switch (seg) {
        case 0: s = x;  d = xh;            break;
        case 1: s = wq; d = w3h;           sc = 0.18033688011112042f; break;
        case 2: s = wk; d = w3h + 262144;  break;
        case 3: s = wv; d = w3h + 524288;  break;
        default: s = wo; d = woh;          break;
    }
    int i = (blk * 256 + threadIdx.x) * 4;
    float4 v = *(const float4*)(s + i);
    f16x4 o;
    o.x = (f16)(v.x * sc); o.y = (f16)(v.y * sc);
    o.z = (f16)(v.z * sc); o.w = (f16)(v.w * sc);
    *(f16x4*)(d + i) = o;
}

// ---------------- fused QKV MFMA GEMM (BK=64) --------------------------------
// C[8192][1536] = xh @ w3h^T. 128x128 tile, BK=64 (8 iters), gl2lds w16,
// 8-chunk XOR-swizzled LDS. grid (12, 64), block 256 (4 waves 2x2).
__global__ __launch_bounds__(256) void gemm_qkv_f16(
    const f16* __restrict__ A, const f16* __restrict__ B,
    f16* __restrict__ qh, f16* __restrict__ kh, f16* __restrict__ vth)
{
    __shared__ __align__(16) char smem[32768];   // A 16K | B 16K ; Tv reuse
    f16* Ash = (f16*)smem;
    f16* Bsh = (f16*)(smem + 16384);

    const int tid = threadIdx.x;
    const int w = tid >> 6, lane = tid & 63;
    const int quad = lane >> 4, low = lane & 15;
    const int wm = w >> 1, wn = w & 1;
    const int m0 = blockIdx.y * 128, n0 = blockIdx.x * 128;

    f32x4 acc[4][4];
    #pragma unroll
    for (int i = 0; i < 4; i++)
        #pragma unroll
        for (int j = 0; j < 4; j++) acc[i][j] = (f32x4){0.f, 0.f, 0.f, 0.f};

    #pragma unroll 1
    for (int k0 = 0; k0 < DIMsz; k0 += 64) {
        __syncthreads();
        #pragma unroll
        for (int j = 0; j < 4; j++) {
            int t = j * 256 + tid;
            int r = t >> 3, g = t & 7;                 // 128 rows x 8 chunks
            int gc = (g ^ (r & 7)) * 8;
            char* lb = (char*)Ash + (j * 256 + w * 64) * 16;
            gl2lds16(A + (size_t)(m0 + r) * DIMsz + k0 + gc, lb);
            char* lb2 = (char*)Bsh + (j * 256 + w * 64) * 16;
            gl2lds16(B + (size_t)(n0 + r) * DIMsz + k0 + gc, lb2);
        }
        __syncthreads();

        #pragma unroll
        for (int ks2 = 0; ks2 < 2; ks2++) {
            f16x8 af[4], bf[4];
            #pragma unroll
            for (int mt = 0; mt < 4; mt++) {
                int ar = wm * 64 + mt * 16 + low;
                int c = ks2 * 4 + quad;
                af[mt] = *(const f16x8*)&Ash[ar * 64 + ((c ^ (ar & 7)) << 3)];
            }
            #pragma unroll
            for (int nt = 0; nt < 4; nt++) {
                int br = wn * 64 + nt * 16 + low;
                int c = ks2 * 4 + quad;
                bf[nt] = *(const f16x8*)&Bsh[br * 64 + ((c ^ (br & 7)) << 3)];
            }
            #pragma unroll
            for (int mt = 0; mt < 4; mt++)
                #pragma unroll
                for (int nt = 0; nt < 4; nt++)
                    acc[mt][nt] = __builtin_amdgcn_mfma_f32_16x16x32_f16(
                        af[mt], bf[nt], acc[mt][nt], 0, 0, 0);
        }
    }

    const int proj = n0 >> 9;                 // uniform per block
    if (proj < 2) {
        f16* dst = (proj == 0) ? qh : kh;
        #pragma unroll
        for (int nt = 0; nt < 4; nt++) {
            int n = n0 + wn * 64 + nt * 16 + low;
            int c = n & 511, h = c >> 6, d = c & 63;
            #pragma unroll
            for (int mt = 0; mt < 4; mt++)
                #pragma unroll
                for (int r = 0; r < 4; r++) {
                    int m = m0 + wm * 64 + mt * 16 + quad * 4 + r;
                    int b_ = m >> 11, l = m & (Lsz - 1);
                    size_t bh = (size_t)(b_ * Hsz + h);
                    dst[(bh * Lsz + l) * Dsz + d] = (f16)acc[mt][nt][r];
                }
        }
    } else {
        // v: transpose per head through LDS, then coalesced stores
        const int hb = (n0 & 511) >> 6;
        f16* Tv = (f16*)smem;                 // [64 d][136]
        const int b_ = m0 >> 11, l0 = m0 & (Lsz - 1);
        #pragma unroll 1
        for (int hs = 0; hs < 2; hs++) {
            __syncthreads();
            if (wn == hs) {
                #pragma unroll
                for (int nt = 0; nt < 4; nt++) {
                    int d = nt * 16 + low;
                    #pragma unroll
                    for (int mt = 0; mt < 4; mt++)
                        #pragma unroll
                        for (int r = 0; r < 4; r++) {
                            int l = wm * 64 + mt * 16 + quad * 4 + r;
                            Tv[d * 136 + l] = (f16)acc[mt][nt][r];
                        }
                }
            }
            __syncthreads();
            int d = tid >> 2, seg = tid & 3;
            size_t bh = (size_t)(b_ * Hsz + hb + hs);
            f16* dstp = vth + (bh * 64 + d) * (size_t)Lsz + l0 + seg * 32;
            const f16* srcp = Tv + d * 136 + seg * 32;
            #pragma unroll
            for (int j = 0; j < 4; j++)
                *(f16x8*)(dstp + j * 8) = *(const f16x8*)(srcp + j * 8);
        }
    }
}

// ---------------- MFMA flash attention (32x32x16, 128-key rounds) ------------
// grid (B*H=32 fastest -> XCD locality, L/64=32), block 256 = 4 waves.
// Waves {0,1} share q-tile 0 (32 q), {2,3} q-tile 1; wave kw owns keys
// kw*32..+31 of each 64-key sub-chunk (split-K; merged at end). 128 keys
// staged per barrier round (half the drains). P C->B via permlane32_swap.
__global__ __launch_bounds__(256) void attn_mfma(
    const f16* __restrict__ q, const f16* __restrict__ k,
    const f16* __restrict__ vt, f16* __restrict__ ctx)
{
    __shared__ __align__(16) char smem[32768];   // Ks 16K | Vs 16K ; O-merge
    __shared__ float Ls[2][32];                  // cross-wave lsum merge

    f16* Ks = (f16*)smem;             // [128 key][64 d], 8-chunk XOR swizzle
    f16* Vs = (f16*)(smem + 16384);   // [64 d][128 key], 16-chunk XOR swizzle

    const int tid = threadIdx.x;
    const int w = tid >> 6, lane = tid & 63;
    const int col = lane & 31;       // q column
    const int h = lane >> 5;         // half-wave
    const int bh = blockIdx.x;       // fastest -> 4 heads per XCD
    const int qb = blockIdx.y;
    const int grp = w >> 1;          // q-tile within block
    const int kw = w & 1;            // owned key half
    const int q0w = qb * 64 + grp * 32;
    const size_t kvb = (size_t)bh * Lsz;

    // Q B-frags: B[k=d][n=q]: lane n=col, k = s*16 + h*8 + j
    f16x8 qf[4];
    #pragma unroll
    for (int s = 0; s < 4; s++)
        qf[s] = *(const f16x8*)(q + (kvb + q0w + col) * Dsz + s * 16 + h * 8);

    f32x16 acc[2];                   // O^T partials: [dt][reg], cols=q
    #pragma unroll
    for (int dt = 0; dt < 2; dt++)
        #pragma unroll
        for (int i = 0; i < 16; i++) acc[dt][i] = 0.f;
    float lsum = 0.f;

    #pragma unroll 1
    for (int s0 = 0; s0 < Lsz; s0 += 128) {
        __syncthreads();
        #pragma unroll
        for (int i = 0; i < 4; i++) {
            int idx = i * 256 + tid;
            int rk = idx >> 3, gk = idx & 7;            // Ks: 128 x 8 chunks
            int rv = idx >> 4, gv = idx & 15;           // Vs: 64 x 16 chunks
            char* kl = (char*)Ks + (i * 256 + w * 64) * 16;
            char* vl = (char*)Vs + (i * 256 + w * 64) * 16;
            gl2lds16(k + (kvb + s0 + rk) * Dsz + ((gk ^ (rk & 7)) << 3), kl);
            gl2lds16(vt + ((size_t)bh * Dsz + rv) * Lsz + s0 + ((gv ^ (rv & 15)) << 3), vl);
        }
        __syncthreads();

        #pragma unroll
        for (int sc = 0; sc < 2; sc++) {
            // ---- S^T (own 32 keys x 32 q): A = K rows, 4 k-steps over d ----
            f32x16 st;
            #pragma unroll
            for (int i = 0; i < 16; i++) st[i] = 0.f;
            const int rk = sc * 64 + kw * 32 + col;
            #pragma unroll
            for (int s = 0; s < 4; s++) {
                f16x8 kf = *(const f16x8*)(Ks + rk * 64 +
                               (((s * 2 + h) ^ (rk & 7)) << 3));
                st = __builtin_amdgcn_mfma_f32_32x32x16_f16(kf, qf[s], st, 0, 0, 0);
            }

            // ---- p = exp2(s); diag zero (wave-uniform test) ----
            float pv[16];
            #pragma unroll
            for (int i = 0; i < 16; i++) pv[i] = EXP2(st[i]);
            if (s0 + sc * 64 == qb * 64 && kw == grp) {
                #pragma unroll
                for (int i = 0; i < 16; i++) {
                    int row = (i & 3) + 8 * (i >> 2) + 4 * h;
                    pv[i] = (row == col) ? 0.f : pv[i];
                }
            }
            #pragma unroll
            for (int i = 0; i < 16; i++) lsum += pv[i];

            // ---- pack pairs; C->B transform in registers ----
            u32 P2[8];
            #pragma unroll
            for (int j = 0; j < 8; j++)
                P2[j] = pack2(pv[2 * j], pv[2 * j + 1]);
            plswap(P2[0], P2[2]); plswap(P2[1], P2[3]);
            plswap(P2[4], P2[6]); plswap(P2[5], P2[7]);
            union { u32 u[4]; f16x8 v; } pf[2];
            #pragma unroll
            for (int jj = 0; jj < 4; jj++) { pf[0].u[jj] = P2[jj]; pf[1].u[jj] = P2[4 + jj]; }

            // ---- O^T += V^T . P over own 32 keys ----
            #pragma unroll
            for (int dt = 0; dt < 2; dt++) {
                const int rv = dt * 32 + col;
                #pragma unroll
                for (int ks = 0; ks < 2; ks++) {
                    int cv = sc * 8 + kw * 4 + ks * 2 + h;
                    f16x8 vf = *(const f16x8*)(Vs + rv * 128 +
                                   ((cv ^ (rv & 15)) << 3));
                    acc[dt] = __builtin_amdgcn_mfma_f32_32x32x16_f16(
                        vf, pf[ks].v, acc[dt], 0, 0, 0);
                }
            }
        }
    }

    lsum += __shfl_xor(lsum, 32);    // reduce over half-wave split of keys

    // ---- cross-wave split-K merge through reused staging LDS (fp32) ----
    __syncthreads();
    float* Om = (float*)smem;        // [grp][64 d][32 q] = 16 KB
    if (kw == 1) {
        float* og = Om + grp * 64 * 32;
        #pragma unroll
        for (int dt = 0; dt < 2; dt++)
            #pragma unroll
            for (int i = 0; i < 16; i++) {
                int row = (i & 3) + 8 * (i >> 2) + 4 * h;
                og[(dt * 32 + row) * 32 + col] = acc[dt][i];
            }
        if (h == 0) Ls[grp][col] = lsum;
    }
    __syncthreads();
    if (kw == 0) {
        const float* og = Om + grp * 64 * 32;
        #pragma unroll
        for (int dt = 0; dt < 2; dt++)
            #pragma unroll
            for (int i = 0; i < 16; i++) {
                int row = (i & 3) + 8 * (i >> 2) + 4 * h;
                acc[dt][i] += og[(dt * 32 + row) * 32 + col];
            }
        lsum += Ls[grp][col];
        const float inv = 1.0f / lsum;

        const int b = bh >> 3, hh = bh & 7;
        f16* op = ctx + ((size_t)(b * Lsz + q0w + col)) * DIMsz + hh * 64;
        #pragma unroll
        for (int dt = 0; dt < 2; dt++)
            #pragma unroll
            for (int r4 = 0; r4 < 4; r4++) {
                f16x4 o;
                o.x = (f16)(acc[dt][4 * r4 + 0] * inv);
                o.y = (f16)(acc[dt][4 * r4 + 1] * inv);
                o.z = (f16)(acc[dt][4 * r4 + 2] * inv);
                o.w = (f16)(acc[dt][4 * r4 + 3] * inv);
                *(f16x4*)(op + dt * 32 + 8 * r4 + 4 * h) = o;
            }
    }
}

// ---------------- out-proj MFMA GEMM: out(fp32) = ctx @ wo^T -----------------
// 64x64 tiles, BK=64 (8 iters), grid (8, 128) = 1024 blocks (4/CU).
__global__ __launch_bounds__(256) void gemm_out_f16(
    const f16* __restrict__ A, const f16* __restrict__ B,
    float* __restrict__ C)
{
    __shared__ f16 Ash[64 * 64];
    __shared__ f16 Bsh[64 * 64];
    const int tid = threadIdx.x;
    const int w = tid >> 6, lane = tid & 63;
    const int quad = lane >> 4, low = lane & 15;
    const int wm = w >> 1, wn = w & 1;
    const int m0 = blockIdx.y * 64, n0 = blockIdx.x * 64;

    f32x4 acc[2][2];
    #pragma unroll
    for (int i = 0; i < 2; i++)
        #pragma unroll
        for (int j = 0; j < 2; j++) acc[i][j] = (f32x4){0.f, 0.f, 0.f, 0.f};

    #pragma unroll 1
    for (int k0 = 0; k0 < DIMsz; k0 += 64) {
        __syncthreads();
        #pragma unroll
        for (int j = 0; j < 2; j++) {
            int t = j * 256 + tid;
            int r = t >> 3, g = t & 7;                 // 64 rows x 8 chunks
            int gc = (g ^ (r & 7)) * 8;
            char* lb = (char*)Ash + (j * 256 + w * 64) * 16;
            gl2lds16(A + (size_t)(m0 + r) * DIMsz + k0 + gc, lb);
            char* lb2 = (char*)Bsh + (j * 256 + w * 64) * 16;
            gl2lds16(B + (size_t)(n0 + r) * DIMsz + k0 + gc, lb2);
        }
        __syncthreads();

        #pragma unroll
        for (int ks2 = 0; ks2 < 2; ks2++) {
            f16x8 af[2], bf[2];
            #pragma unroll
            for (int mt = 0; mt < 2; mt++) {
                int ar = wm * 32 + mt * 16 + low;
                int c = ks2 * 4 + quad;
                af[mt] = *(const f16x8*)&Ash[ar * 64 + ((c ^ (ar & 7)) << 3)];
            }
            #pragma unroll
            for (int nt = 0; nt < 2; nt++) {
                int br = wn * 32 + nt * 16 + low;
                int c = ks2 * 4 + quad;
                bf[nt] = *(const f16x8*)&Bsh[br * 64 + ((c ^ (br & 7)) << 3)];
            }
            #pragma unroll
            for (int mt = 0; mt < 2; mt++)
                #pragma unroll
                for (int nt = 0; nt < 2; nt++)
                    acc[mt][nt] = __builtin_amdgcn_mfma_f32_16x16x32_f16(
                        af[mt], bf[nt], acc[mt][nt], 0, 0, 0);
        }
    }

    #pragma unroll
    for (int mt = 0; mt < 2; mt++)
        #pragma unroll
        for (int r = 0; r < 4; r++) {
            int m = m0 + wm * 32 + mt * 16 + quad * 4 + r;
            #pragma unroll
            for (int nt = 0; nt < 2; nt++) {
                int n = n0 + wn * 32 + nt * 16 + low;
                C[(size_t)m * DIMsz + n] = acc[mt][nt][r];
            }
        }
}

extern "C" void kernel_launch(void* const* d_in, const int* in_sizes, int n_in,
                              void* d_out, int out_size, void* d_ws, size_t ws_size,
                              hipStream_t stream) {
    const float* x  = (const float*)d_in[0];
    const float* wq = (const float*)d_in[1];
    const float* wk = (const float*)d_in[2];
    const float* wv = (const float*)d_in[3];
    const float* wo = (const float*)d_in[4];
    float* out = (float*)d_out;

    const size_t NTOK = (size_t)Bsz * Lsz;   // 8192
    const size_t XSZ  = NTOK * DIMsz;        // 4,194,304

    f16* xh   = (f16*)d_ws;                  // 8 MB
    f16* w3h  = xh + XSZ;                    // 1.5 MB  [1536][512]
    f16* woh  = w3h + 3 * 262144;            // 0.5 MB
    f16* qh   = woh + 262144;                // 8 MB [bh][l][d] (scale*log2e)
    f16* kh   = qh + XSZ;                    // 8 MB [bh][l][d]
    f16* vth  = kh + XSZ;                    // 8 MB [bh][d][l]
    f16* ctxh = vth + XSZ;                   // 8 MB [b*l][512]

    pack_f16<<<5120, 256, 0, stream>>>(x, wq, wk, wv, wo, xh, w3h, woh);

    dim3 g1(1536 / 128, NTOK / 128);         // (12, 64)
    gemm_qkv_f16<<<g1, 256, 0, stream>>>(xh, w3h, qh, kh, vth);

    dim3 g2(Bsz * Hsz, Lsz / 64);            // (32 bh, 32 qb) — bh fastest
    attn_mfma<<<g2, 256, 0, stream>>>(qh, kh, vth, ctxh);

    dim3 g3(DIMsz / 64, NTOK / 64);          // (8, 128)
    gemm_out_f16<<<g3, 256, 0, stream>>>(ctxh, woh, out);
}

// Round 14
// 166.594 us; speedup vs baseline: 1.0835x; 1.0112x over previous
//
#include <hip/hip_runtime.h>
#include <hip/hip_bf16.h>

// B=4, L=2048, DIM=512, H=8, D=64, fp32 in/out.
// pack fp32->fp16 (log2e folded into wq) -> fused QKV MFMA GEMM (BK=64, V^T
// via in-LDS transpose epilogue) -> 32x32x16-MFMA flash attn (64q/wave,
// 4-way key-split waves, 128-key rounds, loop-invariant LDS addressing,
// permlane32_swap P-transform) -> out-proj MFMA GEMM.
// NOTE: global_load_lds imm offset applies to the GLOBAL address only; the
// LDS dest is always M0 + lane*16 -> multi-call staging must bump BOTH ptrs.

#define Bsz 4
#define Lsz 2048
#define DIMsz 512
#define Hsz 8
#define Dsz 64

typedef _Float16 f16;
typedef __attribute__((ext_vector_type(8))) _Float16 f16x8;
typedef __attribute__((ext_vector_type(4))) _Float16 f16x4;
typedef __attribute__((ext_vector_type(2))) __fp16 fp16x2;  // builtin ret type
typedef __attribute__((ext_vector_type(4))) float f32x4;
typedef __attribute__((ext_vector_type(16))) float f32x16;
typedef unsigned int u32;
typedef __attribute__((ext_vector_type(2))) unsigned int u32x2;

#if __has_builtin(__builtin_amdgcn_exp2f)
#define EXP2(x) __builtin_amdgcn_exp2f(x)
#else
#define EXP2(x) __expf(0.6931471805599453f * (x))
#endif

__device__ __forceinline__ u32 pack2(float a, float b) {
#if __has_builtin(__builtin_amdgcn_cvt_pkrtz)
    fp16x2 h = __builtin_amdgcn_cvt_pkrtz(a, b);
    return __builtin_bit_cast(u32, h);
#else
    fp16x2 h; h.x = (__fp16)a; h.y = (__fp16)b;
    return __builtin_bit_cast(u32, h);
#endif
}

// Cross-half exchange for the 32x32 C->B P-transform.
#if __has_builtin(__builtin_amdgcn_permlane32_swap)
__device__ __forceinline__ void plswap(u32& a, u32& b) {
    u32x2 r = __builtin_amdgcn_permlane32_swap(a, b, false, false);
    a = r.x; b = r.y;
}
#else
__device__ __forceinline__ void plswap(u32& a, u32& b) {
    u32 sa = (u32)__shfl_xor((int)a, 32);
    u32 sb = (u32)__shfl_xor((int)b, 32);
    bool hi = (threadIdx.x & 32) != 0;
    u32 na = hi ? sb : a;
    u32 nb = hi ? b : sa;
    a = na; b = nb;
}
#endif

__device__ __forceinline__ void gl2lds16(const void* g, void* l) {
    __builtin_amdgcn_global_load_lds(
        (const __attribute__((address_space(1))) u32*)g,
        (__attribute__((address_space(3))) u32*)l, 16, 0, 0);
}

// ---------------- pack: fp32 -> fp16 ----------------------------------------
__global__ __launch_bounds__(256) void pack_f16(
    const float* __restrict__ x, const float* __restrict__ wq,
    const float* __restrict__ wk, const float* __restrict__ wv,
    const float* __restrict__ wo,
    f16* __restrict__ xh, f16* __restrict__ w3h, f16* __restrict__ woh)
{
    int bx = blockIdx.x, seg, blk;
    if (bx < 4096) { seg = 0; blk = bx; }
    else { seg = 1 + ((bx - 4096) >> 8); blk = (bx - 4096) & 255; }
    const float* s; f16* d; float sc = 1.0f;
    switch (seg) {
        case 0: s = x;  d = xh;            break;
        case 1: s = wq; d = w3h;           sc = 0.18033688011112042f; break;
        case 2: s = wk; d = w3h + 262144;  break;
        case 3: s = wv; d = w3h + 524288;  break;
        default: s = wo; d = woh;          break;
    }
    int i = (blk * 256 + threadIdx.x) * 4;
    float4 v = *(const float4*)(s + i);
    f16x4 o;
    o.x = (f16)(v.x * sc); o.y = (f16)(v.y * sc);
    o.z = (f16)(v.z * sc); o.w = (f16)(v.w * sc);
    *(f16x4*)(d + i) = o;
}

// ---------------- fused QKV MFMA GEMM (BK=64) --------------------------------
__global__ __launch_bounds__(256) void gemm_qkv_f16(
    const f16* __restrict__ A, const f16* __restrict__ B,
    f16* __restrict__ qh, f16* __restrict__ kh, f16* __restrict__ vth)
{
    __shared__ __align__(16) char smem[32768];   // A 16K | B 16K ; Tv reuse
    f16* Ash = (f16*)smem;
    f16* Bsh = (f16*)(smem + 16384);

    const int tid = threadIdx.x;
    const int w = tid >> 6, lane = tid & 63;
    const int quad = lane >> 4, low = lane & 15;
    const int wm = w >> 1, wn = w & 1;
    const int m0 = blockIdx.y * 128, n0 = blockIdx.x * 128;

    f32x4 acc[4][4];
    #pragma unroll
    for (int i = 0; i < 4; i++)
        #pragma unroll
        for (int j = 0; j < 4; j++) acc[i][j] = (f32x4){0.f, 0.f, 0.f, 0.f};

    #pragma unroll 1
    for (int k0 = 0; k0 < DIMsz; k0 += 64) {
        __syncthreads();
        #pragma unroll
        for (int j = 0; j < 4; j++) {
            int t = j * 256 + tid;
            int r = t >> 3, g = t & 7;                 // 128 rows x 8 chunks
            int gc = (g ^ (r & 7)) * 8;
            char* lb = (char*)Ash + (j * 256 + w * 64) * 16;
            gl2lds16(A + (size_t)(m0 + r) * DIMsz + k0 + gc, lb);
            char* lb2 = (char*)Bsh + (j * 256 + w * 64) * 16;
            gl2lds16(B + (size_t)(n0 + r) * DIMsz + k0 + gc, lb2);
        }
        __syncthreads();

        #pragma unroll
        for (int ks2 = 0; ks2 < 2; ks2++) {
            f16x8 af[4], bf[4];
            #pragma unroll
            for (int mt = 0; mt < 4; mt++) {
                int ar = wm * 64 + mt * 16 + low;
                int c = ks2 * 4 + quad;
                af[mt] = *(const f16x8*)&Ash[ar * 64 + ((c ^ (ar & 7)) << 3)];
            }
            #pragma unroll
            for (int nt = 0; nt < 4; nt++) {
                int br = wn * 64 + nt * 16 + low;
                int c = ks2 * 4 + quad;
                bf[nt] = *(const f16x8*)&Bsh[br * 64 + ((c ^ (br & 7)) << 3)];
            }
            #pragma unroll
            for (int mt = 0; mt < 4; mt++)
                #pragma unroll
                for (int nt = 0; nt < 4; nt++)
                    acc[mt][nt] = __builtin_amdgcn_mfma_f32_16x16x32_f16(
                        af[mt], bf[nt], acc[mt][nt], 0, 0, 0);
        }
    }

    const int proj = n0 >> 9;                 // uniform per block
    if (proj < 2) {
        f16* dst = (proj == 0) ? qh : kh;
        #pragma unroll
        for (int nt = 0; nt < 4; nt++) {
            int n = n0 + wn * 64 + nt * 16 + low;
            int c = n & 511, h = c >> 6, d = c & 63;
            #pragma unroll
            for (int mt = 0; mt < 4; mt++)
                #pragma unroll
                for (int r = 0; r < 4; r++) {
                    int m = m0 + wm * 64 + mt * 16 + quad * 4 + r;
                    int b_ = m >> 11, l = m & (Lsz - 1);
                    size_t bh = (size_t)(b_ * Hsz + h);
                    dst[(bh * Lsz + l) * Dsz + d] = (f16)acc[mt][nt][r];
                }
        }
    } else {
        // v: transpose per head through LDS, then coalesced stores
        const int hb = (n0 & 511) >> 6;
        f16* Tv = (f16*)smem;                 // [64 d][136]
        const int b_ = m0 >> 11, l0 = m0 & (Lsz - 1);
        #pragma unroll 1
        for (int hs = 0; hs < 2; hs++) {
            __syncthreads();
            if (wn == hs) {
                #pragma unroll
                for (int nt = 0; nt < 4; nt++) {
                    int d = nt * 16 + low;
                    #pragma unroll
                    for (int mt = 0; mt < 4; mt++)
                        #pragma unroll
                        for (int r = 0; r < 4; r++) {
                            int l = wm * 64 + mt * 16 + quad * 4 + r;
                            Tv[d * 136 + l] = (f16)acc[mt][nt][r];
                        }
                }
            }
            __syncthreads();
            int d = tid >> 2, seg = tid & 3;
            size_t bh = (size_t)(b_ * Hsz + hb + hs);
            f16* dstp = vth + (bh * 64 + d) * (size_t)Lsz + l0 + seg * 32;
            const f16* srcp = Tv + d * 136 + seg * 32;
            #pragma unroll
            for (int j = 0; j < 4; j++)
                *(f16x8*)(dstp + j * 8) = *(const f16x8*)(srcp + j * 8);
        }
    }
}

// ---------------- MFMA flash attention (64q/wave, 4-way key split) -----------
// grid (B*H=32 fastest -> XCD locality, L/64=32), block 256 = 4 waves = 64 q.
// Each round stages 128 keys; wave w owns keys w*32..+31 and computes them
// against ALL 64 q (2 B-operand q-tiles) -> K/V frag reads amortize 2x.
// 4-way split-K O/lsum merge via reused staging LDS at the end. All LDS frag
// addresses + staging sources are loop-invariant (pointer-bumped).
__global__ __launch_bounds__(256, 3) void attn_mfma(
    const f16* __restrict__ q, const f16* __restrict__ k,
    const f16* __restrict__ vt, f16* __restrict__ ctx)
{
    __shared__ __align__(16) char smem[32768];   // Ks 16K | Vs 16K ; O-merge
    __shared__ float Ls[4][2][32];               // per-wave lsum partials

    f16* Ks = (f16*)smem;             // [128 key][64 d], 8-chunk XOR swizzle
    f16* Vs = (f16*)(smem + 16384);   // [64 d][128 key], 16-chunk XOR swizzle

    const int tid = threadIdx.x;
    const int w = tid >> 6, lane = tid & 63;
    const int col = lane & 31;
    const int h = lane >> 5;
    const int bh = blockIdx.x;        // fastest -> 4 heads per XCD
    const int qb = blockIdx.y;
    const int q0 = qb * 64;
    const size_t kvb = (size_t)bh * Lsz;

    // Q B-frags for 2 q-tiles: B[k=d][n=q], lane n=col, k = s*16 + h*8 + j
    f16x8 qf[2][4];
    #pragma unroll
    for (int qt = 0; qt < 2; qt++)
        #pragma unroll
        for (int s = 0; s < 4; s++)
            qf[qt][s] = *(const f16x8*)(q + (kvb + q0 + qt * 32 + col) * Dsz
                                          + s * 16 + h * 8);

    // staging source base pointers (lane-specific, bumped per round)
    const f16* kp; const f16* vp;
    {
        int rk = tid >> 3, gk = tid & 7;          // kp covers rows 0..31
        kp = k + (kvb + rk) * Dsz + ((gk ^ (rk & 7)) << 3);
        int rv = tid >> 4, gv = tid & 15;         // vp covers rows 0..15
        vp = vt + ((size_t)bh * Dsz + rv) * Lsz + ((gv ^ (rv & 15)) << 3);
    }
    char* kl = (char*)Ks + (w * 64) * 16;         // wave-uniform LDS dests
    char* vl = (char*)Vs + (w * 64) * 16;

    // loop-invariant LDS frag pointers
    const int rk = w * 32 + col;                  // wave's key rows
    const f16* kfp[4];
    #pragma unroll
    for (int s = 0; s < 4; s++)
        kfp[s] = Ks + rk * 64 + (((s * 2 + h) ^ (rk & 7)) << 3);
    const f16* vfp[2][2];
    #pragma unroll
    for (int dt = 0; dt < 2; dt++)
        #pragma unroll
        for (int ks = 0; ks < 2; ks++) {
            int rv = dt * 32 + col, cv = w * 4 + ks * 2 + h;
            vfp[dt][ks] = Vs + rv * 128 + ((cv ^ (rv & 15)) << 3);
        }

    f32x16 acc[2][2];                 // O^T partial [qt][dt], cols = q
    #pragma unroll
    for (int qt = 0; qt < 2; qt++)
        #pragma unroll
        for (int dt = 0; dt < 2; dt++)
            #pragma unroll
            for (int i = 0; i < 16; i++) acc[qt][dt][i] = 0.f;
    float lsum[2] = {0.f, 0.f};

    const int drd_s0 = (qb >> 1) * 128;           // round containing the diag
    const int dqt = w - (qb & 1) * 2;             // qt this wave diag-masks

    #pragma unroll 1
    for (int s0 = 0; s0 < Lsz; s0 += 128) {
        __syncthreads();
        // K: +32 rows per call = +2048 f16 global, +4096 B LDS
        gl2lds16(kp,        kl);
        gl2lds16(kp + 2048, kl + 4096);
        gl2lds16(kp + 4096, kl + 8192);
        gl2lds16(kp + 6144, kl + 12288);
        // V: +16 rows per call, +4096 B LDS
        gl2lds16(vp,            vl);
        gl2lds16(vp + 16 * Lsz, vl + 4096);
        gl2lds16(vp + 32 * Lsz, vl + 8192);
        gl2lds16(vp + 48 * Lsz, vl + 12288);
        kp += 128 * Dsz;                                  // next 128 keys
        vp += 128;
        __syncthreads();

        // ---- S^T: A = own 32 K rows, B = both q-tiles; 4 k-steps over d ----
        f32x16 st[2];
        #pragma unroll
        for (int i = 0; i < 16; i++) { st[0][i] = 0.f; st[1][i] = 0.f; }
        #pragma unroll
        for (int s = 0; s < 4; s++) {
            f16x8 kf = *(const f16x8*)kfp[s];
            st[0] = __builtin_amdgcn_mfma_f32_32x32x16_f16(kf, qf[0][s], st[0], 0, 0, 0);
            st[1] = __builtin_amdgcn_mfma_f32_32x32x16_f16(kf, qf[1][s], st[1], 0, 0, 0);
        }

        // ---- softmax numerators + C->B transform per q-tile ----
        union { u32 u[4]; f16x8 v; } pf[2][2];
        const bool drnd = (s0 == drd_s0);
        #pragma unroll
        for (int qt = 0; qt < 2; qt++) {
            float pv[16];
            #pragma unroll
            for (int i = 0; i < 16; i++) pv[i] = EXP2(st[qt][i]);
            if (drnd && qt == dqt) {
                #pragma unroll
                for (int i = 0; i < 16; i++) {
                    int row = (i & 3) + 8 * (i >> 2) + 4 * h;
                    pv[i] = (row == col) ? 0.f : pv[i];
                }
            }
            #pragma unroll
            for (int i = 0; i < 16; i++) lsum[qt] += pv[i];
            u32 P2[8];
            #pragma unroll
            for (int j = 0; j < 8; j++)
                P2[j] = pack2(pv[2 * j], pv[2 * j + 1]);
            plswap(P2[0], P2[2]); plswap(P2[1], P2[3]);
            plswap(P2[4], P2[6]); plswap(P2[5], P2[7]);
            #pragma unroll
            for (int jj = 0; jj < 4; jj++) {
                pf[qt][0].u[jj] = P2[jj];
                pf[qt][1].u[jj] = P2[4 + jj];
            }
        }

        // ---- O^T += V^T . P over own 32 keys (V frags reused across qt) ----
        #pragma unroll
        for (int dt = 0; dt < 2; dt++)
            #pragma unroll
            for (int ks = 0; ks < 2; ks++) {
                f16x8 vf = *(const f16x8*)vfp[dt][ks];
                acc[0][dt] = __builtin_amdgcn_mfma_f32_32x32x16_f16(
                    vf, pf[0][ks].v, acc[0][dt], 0, 0, 0);
                acc[1][dt] = __builtin_amdgcn_mfma_f32_32x32x16_f16(
                    vf, pf[1][ks].v, acc[1][dt], 0, 0, 0);
            }
    }

    // lsum: reduce over half-wave, publish per-wave partial
    #pragma unroll
    for (int qt = 0; qt < 2; qt++) {
        lsum[qt] += __shfl_xor(lsum[qt], 32);
        if (h == 0) Ls[w][qt][col] = lsum[qt];
    }

    // ---- 4-way split-K merge via reused staging LDS (2 x 16KB slots) ----
    float* Om = (float*)smem;
    __syncthreads();
    if (w == 1 || w == 3) {
        float* og = Om + (w >> 1) * 4096;
        #pragma unroll
        for (int qt = 0; qt < 2; qt++)
            #pragma unroll
            for (int dt = 0; dt < 2; dt++)
                #pragma unroll
                for (int i = 0; i < 16; i++) {
                    int row = (i & 3) + 8 * (i >> 2) + 4 * h;
                    og[(dt * 32 + row) * 64 + qt * 32 + col] = acc[qt][dt][i];
                }
    }
    __syncthreads();
    if (w == 0 || w == 2) {
        const float* og = Om + (w >> 1) * 4096;
        #pragma unroll
        for (int qt = 0; qt < 2; qt++)
            #pragma unroll
            for (int dt = 0; dt < 2; dt++)
                #pragma unroll
                for (int i = 0; i < 16; i++) {
                    int row = (i & 3) + 8 * (i >> 2) + 4 * h;
                    acc[qt][dt][i] += og[(dt * 32 + row) * 64 + qt * 32 + col];
                }
    }
    __syncthreads();
    if (w == 2) {
        #pragma unroll
        for (int qt = 0; qt < 2; qt++)
            #pragma unroll
            for (int dt = 0; dt < 2; dt++)
                #pragma unroll
                for (int i = 0; i < 16; i++) {
                    int row = (i & 3) + 8 * (i >> 2) + 4 * h;
                    Om[(dt * 32 + row) * 64 + qt * 32 + col] = acc[qt][dt][i];
                }
    }
    __syncthreads();
    if (w == 0) {
        #pragma unroll
        for (int qt = 0; qt < 2; qt++)
            #pragma unroll
            for (int dt = 0; dt < 2; dt++)
                #pragma unroll
                for (int i = 0; i < 16; i++) {
                    int row = (i & 3) + 8 * (i >> 2) + 4 * h;
                    acc[qt][dt][i] += Om[(dt * 32 + row) * 64 + qt * 32 + col];
                }
        const int b = bh >> 3, hh = bh & 7;
        #pragma unroll
        for (int qt = 0; qt < 2; qt++) {
            float ls = Ls[0][qt][col] + Ls[1][qt][col]
                     + Ls[2][qt][col] + Ls[3][qt][col];
            const float inv = 1.0f / ls;
            f16* op = ctx + ((size_t)(b * Lsz + q0 + qt * 32 + col)) * DIMsz
                          + hh * 64;
            #pragma unroll
            for (int dt = 0; dt < 2; dt++)
                #pragma unroll
                for (int r4 = 0; r4 < 4; r4++) {
                    f16x4 o;
                    o.x = (f16)(acc[qt][dt][4 * r4 + 0] * inv);
                    o.y = (f16)(acc[qt][dt][4 * r4 + 1] * inv);
                    o.z = (f16)(acc[qt][dt][4 * r4 + 2] * inv);
                    o.w = (f16)(acc[qt][dt][4 * r4 + 3] * inv);
                    *(f16x4*)(op + dt * 32 + 8 * r4 + 4 * h) = o;
                }
        }
    }
}

// ---------------- out-proj MFMA GEMM: out(fp32) = ctx @ wo^T -----------------
__global__ __launch_bounds__(256) void gemm_out_f16(
    const f16* __restrict__ A, const f16* __restrict__ B,
    float* __restrict__ C)
{
    __shared__ f16 Ash[64 * 64];
    __shared__ f16 Bsh[64 * 64];
    const int tid = threadIdx.x;
    const int w = tid >> 6, lane = tid & 63;
    const int quad = lane >> 4, low = lane & 15;
    const int wm = w >> 1, wn = w & 1;
    const int m0 = blockIdx.y * 64, n0 = blockIdx.x * 64;

    f32x4 acc[2][2];
    #pragma unroll
    for (int i = 0; i < 2; i++)
        #pragma unroll
        for (int j = 0; j < 2; j++) acc[i][j] = (f32x4){0.f, 0.f, 0.f, 0.f};

    #pragma unroll 1
    for (int k0 = 0; k0 < DIMsz; k0 += 64) {
        __syncthreads();
        #pragma unroll
        for (int j = 0; j < 2; j++) {
            int t = j * 256 + tid;
            int r = t >> 3, g = t & 7;                 // 64 rows x 8 chunks
            int gc = (g ^ (r & 7)) * 8;
            char* lb = (char*)Ash + (j * 256 + w * 64) * 16;
            gl2lds16(A + (size_t)(m0 + r) * DIMsz + k0 + gc, lb);
            char* lb2 = (char*)Bsh + (j * 256 + w * 64) * 16;
            gl2lds16(B + (size_t)(n0 + r) * DIMsz + k0 + gc, lb2);
        }
        __syncthreads();

        #pragma unroll
        for (int ks2 = 0; ks2 < 2; ks2++) {
            f16x8 af[2], bf[2];
            #pragma unroll
            for (int mt = 0; mt < 2; mt++) {
                int ar = wm * 32 + mt * 16 + low;
                int c = ks2 * 4 + quad;
                af[mt] = *(const f16x8*)&Ash[ar * 64 + ((c ^ (ar & 7)) << 3)];
            }
            #pragma unroll
            for (int nt = 0; nt < 2; nt++) {
                int br = wn * 32 + nt * 16 + low;
                int c = ks2 * 4 + quad;
                bf[nt] = *(const f16x8*)&Bsh[br * 64 + ((c ^ (br & 7)) << 3)];
            }
            #pragma unroll
            for (int mt = 0; mt < 2; mt++)
                #pragma unroll
                for (int nt = 0; nt < 2; nt++)
                    acc[mt][nt] = __builtin_amdgcn_mfma_f32_16x16x32_f16(
                        af[mt], bf[nt], acc[mt][nt], 0, 0, 0);
        }
    }

    #pragma unroll
    for (int mt = 0; mt < 2; mt++)
        #pragma unroll
        for (int r = 0; r < 4; r++) {
            int m = m0 + wm * 32 + mt * 16 + quad * 4 + r;
            #pragma unroll
            for (int nt = 0; nt < 2; nt++) {
                int n = n0 + wn * 32 + nt * 16 + low;
                C[(size_t)m * DIMsz + n] = acc[mt][nt][r];
            }
        }
}

extern "C" void kernel_launch(void* const* d_in, const int* in_sizes, int n_in,
                              void* d_out, int out_size, void* d_ws, size_t ws_size,
                              hipStream_t stream) {
    const float* x  = (const float*)d_in[0];
    const float* wq = (const float*)d_in[1];
    const float* wk = (const float*)d_in[2];
    const float* wv = (const float*)d_in[3];
    const float* wo = (const float*)d_in[4];
    float* out = (float*)d_out;

    const size_t NTOK = (size_t)Bsz * Lsz;   // 8192
    const size_t XSZ  = NTOK * DIMsz;        // 4,194,304

    f16* xh   = (f16*)d_ws;                  // 8 MB
    f16* w3h  = xh + XSZ;                    // 1.5 MB  [1536][512]
    f16* woh  = w3h + 3 * 262144;            // 0.5 MB
    f16* qh   = woh + 262144;                // 8 MB [bh][l][d] (scale*log2e)
    f16* kh   = qh + XSZ;                    // 8 MB [bh][l][d]
    f16* vth  = kh + XSZ;                    // 8 MB [bh][d][l]
    f16* ctxh = vth + XSZ;                   // 8 MB [b*l][512]

    pack_f16<<<5120, 256, 0, stream>>>(x, wq, wk, wv, wo, xh, w3h, woh);

    dim3 g1(1536 / 128, NTOK / 128);         // (12, 64)
    gemm_qkv_f16<<<g1, 256, 0, stream>>>(xh, w3h, qh, kh, vth);

    dim3 g2(Bsz * Hsz, Lsz / 64);            // (32 bh, 32 qb) — bh fastest
    attn_mfma<<<g2, 256, 0, stream>>>(qh, kh, vth, ctxh);

    dim3 g3(DIMsz / 64, NTOK / 64);          // (8, 128)
    gemm_out_f16<<<g3, 256, 0, stream>>>(ctxh, woh, out);
}